// Round 4
// baseline (79.494 us; speedup 1.0000x reference)
//
#include <hip/hip_runtime.h>
#include <cstddef>

#define NUM_BLOCKS 8
#define BLK 512
#define D_IN 2048
#define NROWS 8192
#define NBUCKETS (NUM_BLOCKS * BLK) /* 4096 */
#define CAP 32                      /* padded capacity per bucket, mult of 4 */
#define ROWS_PER_WG 4
#define THREADS 512
#define XS_ROWS 2052                /* 2048 + sentinel pad rows */
#define SENT_ENT (D_IN << 1)        /* sentinel entry: d=2048, sign + */

// Build inverted index: one WAVE per bucket. Lanes scan 64 dims per step,
// ballot-match, place matches in ascending-d order via popcount prefix into
// row-major entries[bucket][CAP]. Pad to a multiple of 4 with sentinels
// (d=2048 -> zeroed LDS row in the gather kernel). nchunks = #int4 chunks.
__global__ __launch_bounds__(256) void cs_build_index(
    const int* __restrict__ i_hash, const float* __restrict__ s_hash,
    int* __restrict__ nchunks, int* __restrict__ entries)
{
    const int gid  = blockIdx.x * blockDim.x + threadIdx.x;
    const int wave = gid >> 6;            // bucket id in [0, 4096)
    const int lane = threadIdx.x & 63;
    if (wave >= NBUCKETS) return;
    const int b = wave >> 9;
    const int k = wave & (BLK - 1);
    const int*   ih = i_hash + b * D_IN;
    const float* sr = s_hash + b * D_IN;
    int* erow = entries + wave * CAP;
    int cnt = 0;
    for (int d0 = 0; d0 < D_IN; d0 += 64) {
        const int d = d0 + lane;
        const bool m = (ih[d] == k);      // coalesced load
        const unsigned long long mask = __ballot(m);
        if (m) {
            const int pos = cnt + __popcll(mask & ((1ull << lane) - 1ull));
            if (pos < CAP) {
                const int sg = (sr[d] < 0.0f) ? 1 : 0;
                erow[pos] = (d << 1) | sg;
            }
        }
        cnt += (int)__popcll(mask);
    }
    if (cnt > CAP) cnt = CAP;
    int nch = (cnt + 3) >> 2;
    if (nch == 0) nch = 1;                // empty bucket -> 1 all-sentinel chunk
    if (lane >= cnt && lane < nch * 4) erow[lane] = SENT_ENT;
    if (lane == 0) nchunks[wave] = nch;
}

// Gather: LDS holds x TRANSPOSED as xs[d][4 rows] (16 B per input dim), so
// one ds_read_b128 per entry fetches all 4 rows. Bucket loop is software-
// pipelined (prefetch next bucket's nchunks + chunk0). NT output stores.
__global__ __launch_bounds__(THREADS, 8) void cs_gather(
    const float* __restrict__ x, const int* __restrict__ nchunks,
    const int* __restrict__ entries, float* __restrict__ out)
{
    __shared__ float xs[XS_ROWS][4]; // ~32.8 KiB, row d at byte offset 16*d
    const int tid = threadIdx.x;
    const int n0  = blockIdx.x * ROWS_PER_WG;

    // Stage transposed: thread t owns d in {t, t+512, t+1024, t+1536};
    // 4 coalesced dword loads (one per row) -> one stride-16B b128 write.
#pragma unroll
    for (int i = 0; i < 4; ++i) {
        const int d = tid + i * THREADS;
        const size_t base = (size_t)n0 * D_IN + d;
        float4 w;
        w.x = x[base];
        w.y = x[base + D_IN];
        w.z = x[base + 2 * D_IN];
        w.w = x[base + 3 * D_IN];
        *(float4*)&xs[d][0] = w;
    }
    if (tid < XS_ROWS - D_IN)       // zero sentinel rows
        *(float4*)&xs[D_IN + tid][0] = make_float4(0.f, 0.f, 0.f, 0.f);
    __syncthreads();

    const float scale = 0.35355339059327373f; // 1/sqrt(8)

#define PROC(ent)                                                        \
    do {                                                                 \
        const int d = (ent) >> 1;                                        \
        const unsigned sg = ((unsigned)(ent) & 1u) << 31;                \
        const float4 v = *(const float4*)&xs[d][0];   /* ds_read_b128 */ \
        a0 += __uint_as_float(__float_as_uint(v.x) ^ sg);                \
        a1 += __uint_as_float(__float_as_uint(v.y) ^ sg);                \
        a2 += __uint_as_float(__float_as_uint(v.z) ^ sg);                \
        a3 += __uint_as_float(__float_as_uint(v.w) ^ sg);                \
    } while (0)

    int j   = tid;
    int nch = nchunks[j];
    int4 c0 = *(const int4*)(entries + j * CAP);
#pragma unroll 1
    for (int jj = 0; jj < NBUCKETS / THREADS; ++jj) {   // 8 buckets/thread
        int jn = (jj == NBUCKETS / THREADS - 1) ? j : j + THREADS;
        const int  nch_n = nchunks[jn];                 // prefetch next
        const int4 c0_n  = *(const int4*)(entries + jn * CAP);

        float a0 = 0.f, a1 = 0.f, a2 = 0.f, a3 = 0.f;
        PROC(c0.x); PROC(c0.y); PROC(c0.z); PROC(c0.w);
        const int4* __restrict__ ep = (const int4*)(entries + j * CAP);
#pragma unroll 1
        for (int c = 1; c < nch; ++c) {
            int4 cc = ep[c];
            PROC(cc.x); PROC(cc.y); PROC(cc.z); PROC(cc.w);
        }
        const size_t o = (size_t)n0 * NBUCKETS + j;     // coalesced NT stores
        __builtin_nontemporal_store(a0 * scale, &out[o]);
        __builtin_nontemporal_store(a1 * scale, &out[o + NBUCKETS]);
        __builtin_nontemporal_store(a2 * scale, &out[o + 2 * NBUCKETS]);
        __builtin_nontemporal_store(a3 * scale, &out[o + 3 * NBUCKETS]);

        j = jn; nch = nch_n; c0 = c0_n;
    }
#undef PROC
}

extern "C" void kernel_launch(void* const* d_in, const int* in_sizes, int n_in,
                              void* d_out, int out_size, void* d_ws, size_t ws_size,
                              hipStream_t stream)
{
    const float* x      = (const float*)d_in[0];
    const float* s_hash = (const float*)d_in[1];
    const int*   i_hash = (const int*)d_in[2];
    float* out = (float*)d_out;

    // ws layout: nchunks[4096] ints, then entries[4096][CAP] ints (528 KiB)
    int* nchunks = (int*)d_ws;
    int* entries = nchunks + NBUCKETS;

    cs_build_index<<<(NBUCKETS * 64) / 256, 256, 0, stream>>>(i_hash, s_hash, nchunks, entries);
    cs_gather<<<NROWS / ROWS_PER_WG, THREADS, 0, stream>>>(x, nchunks, entries, out);
}